// Round 4
// baseline (150.971 us; speedup 1.0000x reference)
//
#include <hip/hip_runtime.h>
#include <stdint.h>

#define N_NODES 2048
#define N_BATCH 4
#define ROWS_PER_BLOCK 8
#define THREADS 512            // 8 waves, one row per wave
#define NTILES (N_NODES / 256) // 8 tiles of 256 j per row

__device__ __forceinline__ uint32_t bf16rn(float x) {
    uint32_t u = __float_as_uint(x);
    u += 0x7fffu + ((u >> 16) & 1u);
    return u >> 16;
}

// RESUBMIT of round-2 experiment (round-3 bench died to a container
// acquisition failure, not a kernel fault; no counters were produced).
//
// R2 lesson: 1-deep prefetch with a vmcnt(0) drain per iteration convoys at
// ~2.9 TB/s delivered regardless of load width (R0==R2 duration). This
// version maximizes per-wave MLP instead: __launch_bounds__(512,4) lifts the
// VGPR cap to 128, each wave issues its ENTIRE 8 KB row (16x dwordx4) before
// phase 1, and phase 2 consumes tiles in issue order so the compiler emits
// counted vmcnt waits (14,12,...) -- no drain in the hot loop.
// Occupancy: 2 blocks/CU (16 waves) -- intentional trade of TLP for MLP.
__global__ __launch_bounds__(THREADS, 4) void kuramoto_kernel(
    const float* __restrict__ theta,
    const float* __restrict__ gamma,
    const float* __restrict__ W,
    const float* __restrict__ alpha,
    float* __restrict__ out)
{
    // SoA by d: tbl[d][j] = (bf16(cos th_jd)<<16) | bf16(sin th_jd)
    // Lane owns 4 consecutive j -> per-d read is ds_read_b128 at lane
    // stride 16B = conflict-free.
    __shared__ uint32_t tbl[4][N_NODES];

    const int tid  = threadIdx.x;
    const int lane = tid & 63;
    const int wave = tid >> 6;
    const int b    = blockIdx.x >> 8;                      // 256 blocks per batch
    const int i    = ((blockIdx.x & 255) * ROWS_PER_BLOCK) + wave;

    const size_t rowbase = ((size_t)b * N_NODES + i) * N_NODES;
    const float* Wr = W + rowbase;
    const float* Ar = alpha + rowbase;

    // ---- Phase 0: issue the whole row. 8 KB/wave in flight; latency of the
    // first tiles hides under the table build + barrier below.
    float4 wrow[NTILES], arow[NTILES];
    #pragma unroll
    for (int k = 0; k < NTILES; ++k) {
        const int j0 = k * 256 + lane * 4;
        wrow[k] = *(const float4*)(Wr + j0);   // global_load_dwordx4
        arow[k] = *(const float4*)(Ar + j0);
    }

    // ---- Phase 1: stage sin/cos(theta[b,:,:]) into LDS, bf16-packed ----
    const float* thb = theta + (size_t)b * (N_NODES * 4);
    #pragma unroll
    for (int g = 0; g < N_NODES / THREADS; ++g) {
        const int j = tid + g * THREADS;
        const float4 u = *(const float4*)(thb + (size_t)j * 4);  // coalesced
        const float th[4] = {u.x, u.y, u.z, u.w};
        #pragma unroll
        for (int d = 0; d < 4; ++d) {
            float s, c;
            __sincosf(th[d], &s, &c);
            tbl[d][j] = (bf16rn(c) << 16) | bf16rn(s);  // stride 4B: conflict-free
        }
    }
    __syncthreads();

    // ---- Phase 2: consume tiles in issue order (counted vmcnt waits) ----
    //   im_d = sum_j (A*s_jd - B*c_jd),  re_d = sum_j (A*c_jd + B*s_jd)
    //   A = W*cos(alpha), B = W*sin(alpha)
    float re[4] = {0.f, 0.f, 0.f, 0.f};
    float im[4] = {0.f, 0.f, 0.f, 0.f};

    #pragma unroll
    for (int k = 0; k < NTILES; ++k) {           // full unroll: wrow[k]/arow[k]
        const int j0 = k * 256 + lane * 4;       // static indices (no scratch)
        const float wq[4] = {wrow[k].x, wrow[k].y, wrow[k].z, wrow[k].w};
        const float aq[4] = {arow[k].x, arow[k].y, arow[k].z, arow[k].w};
        float A[4], Bq[4];
        #pragma unroll
        for (int q = 0; q < 4; ++q) {
            float sa, ca;
            __sincosf(aq[q], &sa, &ca);
            A[q]  = wq[q] * ca;
            Bq[q] = wq[q] * sa;
        }
        #pragma unroll
        for (int d = 0; d < 4; ++d) {
            const uint4 t = *(const uint4*)&tbl[d][j0];  // one tile live at a time
            const uint32_t tu[4] = {t.x, t.y, t.z, t.w};
            #pragma unroll
            for (int q = 0; q < 4; ++q) {
                const float s = __uint_as_float(tu[q] << 16);
                const float c = __uint_as_float(tu[q] & 0xffff0000u);
                re[d] = fmaf(A[q],   c, re[d]);
                re[d] = fmaf(Bq[q],  s, re[d]);
                im[d] = fmaf(A[q],   s, im[d]);
                im[d] = fmaf(-Bq[q], c, im[d]);
            }
        }
    }

    // ---- Reduction: 6-stage butterfly over 64 lanes, 8 accumulators ----
    #pragma unroll
    for (int stage = 1; stage < 64; stage <<= 1) {
        #pragma unroll
        for (int d = 0; d < 4; ++d) {
            re[d] += __shfl_xor(re[d], stage, 64);
            im[d] += __shfl_xor(im[d], stage, 64);
        }
    }

    if (lane == 0) {
        const size_t obase = ((size_t)b * N_NODES + i) * 4;
        const float4 th4 = *(const float4*)(thb + (size_t)i * 4);
        const float4 g4  = *(const float4*)(gamma + obase);
        const float thd[4] = {th4.x, th4.y, th4.z, th4.w};
        const float gd[4]  = {g4.x, g4.y, g4.z, g4.w};
        float t[4];
        float s2 = 0.0f;
        #pragma unroll
        for (int d = 0; d < 4; ++d) {
            float s_i, c_i;
            __sincosf(thd[d], &s_i, &c_i);
            const float coup = (c_i * im[d] - s_i * re[d]) * (1.0f / (float)N_NODES);
            t[d] = gd[d] + coup;   // theta + (gamma-theta) + coupling  (DT=ATTR=1)
            s2 = fmaf(t[d], t[d], s2);
        }
        const float inv = 1.0f / fmaxf(sqrtf(s2), 1e-6f);
        *(float4*)(out + obase) = make_float4(t[0]*inv, t[1]*inv, t[2]*inv, t[3]*inv);
    }
}

extern "C" void kernel_launch(void* const* d_in, const int* in_sizes, int n_in,
                              void* d_out, int out_size, void* d_ws, size_t ws_size,
                              hipStream_t stream) {
    const float* theta = (const float*)d_in[0];
    const float* gamma = (const float*)d_in[1];
    const float* W     = (const float*)d_in[2];
    const float* alpha = (const float*)d_in[3];
    float* out = (float*)d_out;

    const int grid = (N_BATCH * N_NODES) / ROWS_PER_BLOCK;  // 1024 blocks = 2 rounds of 2/CU
    hipLaunchKernelGGL(kuramoto_kernel, dim3(grid), dim3(THREADS), 0, stream,
                       theta, gamma, W, alpha, out);
}